// Round 10
// baseline (263.035 us; speedup 1.0000x reference)
//
#include <hip/hip_runtime.h>
#include <hip/hip_bf16.h>
#include <math.h>

#define S_LEN 2048
#define DIM   128
#define NHEAD 16
#define BQ    62
#define BK    64
#define SCALE 0.08838834764831845f

typedef __attribute__((ext_vector_type(8))) short bf16x8;
typedef __attribute__((ext_vector_type(4))) float f32x4;
typedef __attribute__((ext_vector_type(2))) float f32x2;

__device__ __forceinline__ short f2bf(float f) {
  union { float f; unsigned u; } v; v.f = f;
  unsigned r = v.u + 0x7fffu + ((v.u >> 16) & 1u);
  return (short)(r >> 16);
}
__device__ __forceinline__ float bhi(unsigned u) {
  union { unsigned v; float f; } x; x.v = u & 0xffff0000u; return x.f;
}
__device__ __forceinline__ float blo(unsigned u) {
  union { unsigned v; float f; } x; x.v = u << 16; return x.f;
}
__device__ __forceinline__ float b2f(short s) {
  union { unsigned v; float f; } x; x.v = ((unsigned)(unsigned short)s) << 16; return x.f;
}
__device__ __forceinline__ unsigned cvtpk(float lo, float hi) {
  unsigned r;
  asm("v_cvt_pk_bf16_f32 %0, %1, %2" : "=v"(r) : "v"(lo), "v"(hi));
  return r;
}
__device__ __forceinline__ f32x2 pkfma(f32x2 a, f32x2 b, f32x2 c) {
  f32x2 d;
  asm("v_pk_fma_f32 %0, %1, %2, %3" : "=v"(d) : "v"(a), "v"(b), "v"(c));
  return d;
}

// ---------- prep 1: K fp32 -> bf16*SCALE, plain row-major (no swizzle) ----------
__global__ __launch_bounds__(256)
void prep_k(const float* __restrict__ K, short* __restrict__ Kb) {
  int gid = blockIdx.x * 256 + threadIdx.x;
  int chunk = gid & 15;
  int row = gid >> 4;                       // h*2048 + k
  const float* src = K + (size_t)row * DIM + chunk * 8;
  float4 a = *(const float4*)(src);
  float4 b = *(const float4*)(src + 4);
  bf16x8 o;
  o[0]=f2bf(a.x*SCALE); o[1]=f2bf(a.y*SCALE); o[2]=f2bf(a.z*SCALE); o[3]=f2bf(a.w*SCALE);
  o[4]=f2bf(b.x*SCALE); o[5]=f2bf(b.y*SCALE); o[6]=f2bf(b.z*SCALE); o[7]=f2bf(b.w*SCALE);
  *(bf16x8*)(Kb + (size_t)row * DIM + chunk * 8) = o;
}

// ---------- prep 2: V fp32 -> V^T bf16 tiles [h][tile64][d][64], plain ----------
__global__ __launch_bounds__(256)
void prep_v(const float* __restrict__ V, short* __restrict__ Vw) {
  __shared__ __align__(16) short lv[128][72];
  int tile = blockIdx.x, h = blockIdx.y;
  const float* src = V + ((size_t)h * S_LEN + tile * 64) * DIM;
  int kr = threadIdx.x >> 2, dc = (threadIdx.x & 3) * 32;
  const float* sp = src + (size_t)kr * DIM + dc;
  #pragma unroll
  for (int j = 0; j < 32; j += 4) {
    float4 v = *(const float4*)(sp + j);
    lv[dc + j][kr]     = f2bf(v.x);
    lv[dc + j + 1][kr] = f2bf(v.y);
    lv[dc + j + 2][kr] = f2bf(v.z);
    lv[dc + j + 3][kr] = f2bf(v.w);
  }
  __syncthreads();
  int d = threadIdx.x >> 1, cbase = (threadIdx.x & 1) * 4;
  short* dst = Vw + ((size_t)h * 32 + tile) * 8192 + (size_t)d * 64;
  #pragma unroll
  for (int c0 = 0; c0 < 4; ++c0) {
    int c = cbase + c0;
    *(bf16x8*)(dst + c * 8) = *(const bf16x8*)&lv[d][c * 8];
  }
}

// ---------- main: R4's proven lag-1 pipeline, staging-free.
// Per (head, q-tile): Phase B = QK^T with B-fragments read DIRECTLY from global
// Kb (L2/L3-resident; each element used once per block, so LDS staging bought
// nothing). masked *pre-scaled* scores -> rawS16[t&1] (bf16 LDS). Phase C =
// packed 3x3 conv + online softmax + PV with V^T fragments DIRECTLY from global
// Vw. LDS = 17.2 KB -> 4-5 blocks/CU (vs R4's 2). Two __syncthreads per iter.
__global__ __launch_bounds__(256, 4)
void convattn_main(const float* __restrict__ Q, const short* __restrict__ Kb,
                   const short* __restrict__ Vw, const float* __restrict__ Wt,
                   float* __restrict__ Out) {
  __shared__ __align__(16) short rawS16[2][64][66];   // 16.5 KB
  __shared__ short haloL16[2][64];                    // 256 B

  const int bx = blockIdx.x;
  const int rank = (bx < 256) ? bx : ((bx < 512) ? (767 - bx) : bx);
  const int qt = 33 - (rank >> 4);                    // longest-first
  const int h  = rank & 15;
  const int q0 = qt * BQ;
  const int qr0 = q0 - 2;
  const int q_cap = min(q0 + BQ - 1, S_LEN - 1);
  const int T = q_cap / BK + 1;

  const int tid  = threadIdx.x;
  const int wid  = tid >> 6;
  const int lane = tid & 63;
  const int lm   = lane & 15;
  const int lg   = lane >> 4;

  const float* Qh = Q + (size_t)h * S_LEN * DIM;
  const short* KbH = Kb + (size_t)h * S_LEN * DIM;
  const short* VwH = Vw + (size_t)h * 32 * 8192;
  float* Oh = Out + (size_t)h * S_LEN * DIM;

  f32x2 wp[9];
  #pragma unroll
  for (int i = 0; i < 9; ++i) { float w = Wt[h * 9 + i]; wp[i][0] = w; wp[i][1] = w; }

  // ---- Q fragments (bf16), hoisted (R4 verbatim) ----
  bf16x8 qf[4];
  {
    int qrow = qr0 + wid * 16 + lm;
    int qc = qrow < 0 ? 0 : (qrow >= S_LEN ? S_LEN - 1 : qrow);
    const float* qp = Qh + (size_t)qc * DIM;
    #pragma unroll
    for (int kk = 0; kk < 4; ++kk) {
      int d0 = kk * 32 + lg * 8;
      float4 a = *(const float4*)(qp + d0);
      float4 b = *(const float4*)(qp + d0 + 4);
      bf16x8 f;
      f[0]=f2bf(a.x); f[1]=f2bf(a.y); f[2]=f2bf(a.z); f[3]=f2bf(a.w);
      f[4]=f2bf(b.x); f[5]=f2bf(b.y); f[6]=f2bf(b.z); f[7]=f2bf(b.w);
      qf[kk] = f;
    }
  }
  if (tid < 64) haloL16[0][tid] = 0;

  float m_state = -INFINITY, l_state = 0.f;
  f32x4 oacc[8];
  const f32x4 zero4 = {0.f, 0.f, 0.f, 0.f};
  #pragma unroll
  for (int cb = 0; cb < 8; ++cb) oacc[cb] = zero4;

  for (int t = 0; t <= T; ++t) {
    __syncthreads();   // B1: protect rawS16[(t)&1] overwrite + haloL swap
    // ---- Phase B: QK^T (B-fragments straight from global) -> masked bf16 tile t ----
    if (t < T) {
      int k0 = t * BK;
      f32x4 sacc[4];
      #pragma unroll
      for (int cb = 0; cb < 4; ++cb) sacc[cb] = zero4;
      #pragma unroll
      for (int kk = 0; kk < 4; ++kk) {
        #pragma unroll
        for (int cb = 0; cb < 4; ++cb) {
          const short* kp = KbH + (size_t)(k0 + cb * 16 + lm) * DIM + (kk * 4 + lg) * 8;
          bf16x8 bf = *(const bf16x8*)kp;
          sacc[cb] = __builtin_amdgcn_mfma_f32_16x16x32_bf16(qf[kk], bf, sacc[cb], 0, 0, 0);
        }
      }
      const int buf = t & 1;
      #pragma unroll
      for (int cb = 0; cb < 4; ++cb) {
        int rr = wid * 16 + lg * 4;
        int cc = cb * 16 + lm;
        #pragma unroll
        for (int i = 0; i < 4; i += 2) {
          float v0 = ((k0 + cc) <= (qr0 + rr + i))     ? sacc[cb][i]     : 0.f;
          float v1 = ((k0 + cc) <= (qr0 + rr + i + 1)) ? sacc[cb][i + 1] : 0.f;
          unsigned pk = cvtpk(v0, v1);
          rawS16[buf][rr + i][cc]     = (short)pk;
          rawS16[buf][rr + i + 1][cc] = (short)(pk >> 16);
        }
      }
    }
    __syncthreads();   // B3: publish rawS16 tile t (right halo + cross-wave rows)
    // ---- Phase C: packed conv + online softmax + PV for tile t-1 (R4 verbatim) ----
    if (t > 0) {
      const int tp = t - 1;
      const int pb = tp & 1, nb = pb ^ 1;
      const int c0p = tp * BK;
      const bool haveRight = (t < T);
      const int r = wid * 16 + lm;
      const int q = qr0 + r;
      const bool rowvalid = (r >= 2) && (q <= q_cap);
      const int a0 = max(r - 2, 0), a1 = max(r - 1, 0);
      const short* rp[3] = { &rawS16[pb][a0][0], &rawS16[pb][a1][0], &rawS16[pb][r][0] };
      const int ridx[3] = { a0, a1, r };
      const int cs0 = lg * 8;
      const int cs1 = 32 + lg * 8;
      const bool leftEdge  = (lg == 0);
      const bool rightEdge = (lg == 3);
      const int cA = leftEdge ? 0 : cs0 - 2;

      f32x2 xv[3][10];
      #pragma unroll
      for (int rw = 0; rw < 3; ++rw) {
        const short* p = rp[rw];
        unsigned a0w = *(const unsigned*)(p + cA);
        unsigned a1w = *(const unsigned*)(p + cs0);
        unsigned a2w = *(const unsigned*)(p + cs0 + 2);
        unsigned a3w = *(const unsigned*)(p + cs0 + 4);
        unsigned a4w = *(const unsigned*)(p + cs0 + 6);
        unsigned a5w = *(const unsigned*)(p + cs0 + 8);
        unsigned b0w = *(const unsigned*)(p + cs1 - 2);
        unsigned b1w = *(const unsigned*)(p + cs1);
        unsigned b2w = *(const unsigned*)(p + cs1 + 2);
        unsigned b3w = *(const unsigned*)(p + cs1 + 4);
        unsigned b4w = *(const unsigned*)(p + cs1 + 6);
        unsigned b5w = *(const unsigned*)(p + cs1 + 8);
        float hv = b2f(haloL16[pb][ridx[rw]]);
        float rv = haveRight ? b2f(rawS16[nb][ridx[rw]][0]) : 0.f;
        xv[rw][0][0] = leftEdge ? hv : bhi(a0w);  xv[rw][0][1] = bhi(b0w);
        xv[rw][1][0] = blo(a1w);  xv[rw][1][1] = blo(b1w);
        xv[rw][2][0] = bhi(a1w);  xv[rw][2][1] = bhi(b1w);
        xv[rw][3][0] = blo(a2w);  xv[rw][3][1] = blo(b2w);
        xv[rw][4][0] = bhi(a2w);  xv[rw][4][1] = bhi(b2w);
        xv[rw][5][0] = blo(a3w);  xv[rw][5][1] = blo(b3w);
        xv[rw][6][0] = bhi(a3w);  xv[rw][6][1] = bhi(b3w);
        xv[rw][7][0] = blo(a4w);  xv[rw][7][1] = blo(b4w);
        xv[rw][8][0] = bhi(a4w);  xv[rw][8][1] = bhi(b4w);
        xv[rw][9][0] = blo(a5w);  xv[rw][9][1] = rightEdge ? rv : blo(b5w);
      }

      const int thr0 = rowvalid ? (q - c0p - cs0) : -1;
      const int thr1 = rowvalid ? (q - c0p - cs1) : -1;
      float svx[8], svy[8];
      float pm = -INFINITY;
      #pragma unroll
      for (int c = 0; c < 8; ++c) {
        f32x2 acc = {0.f, 0.f};
        acc = pkfma(wp[0], xv[0][c],     acc);
        acc = pkfma(wp[1], xv[0][c + 1], acc);
        acc = pkfma(wp[2], xv[0][c + 2], acc);
        acc = pkfma(wp[3], xv[1][c],     acc);
        acc = pkfma(wp[4], xv[1][c + 1], acc);
        acc = pkfma(wp[5], xv[1][c + 2], acc);
        acc = pkfma(wp[6], xv[2][c],     acc);
        acc = pkfma(wp[7], xv[2][c + 1], acc);
        acc = pkfma(wp[8], xv[2][c + 2], acc);
        svx[c] = (c <= thr0) ? acc[0] : -INFINITY;
        svy[c] = (c <= thr1) ? acc[1] : -INFINITY;
        pm = fmaxf(pm, fmaxf(svx[c], svy[c]));
      }
      pm = fmaxf(pm, __shfl_xor(pm, 16));
      pm = fmaxf(pm, __shfl_xor(pm, 32));
      const float mn = fmaxf(m_state, pm);
      const float al = __expf(m_state - mn);
      float ps = 0.f;
      union { bf16x8 v; unsigned u[4]; } pf0u, pf1u;
      #pragma unroll
      for (int c = 0; c < 8; c += 2) {
        float p0 = __expf(svx[c] - mn);
        float p1 = __expf(svx[c + 1] - mn);
        float p2 = __expf(svy[c] - mn);
        float p3 = __expf(svy[c + 1] - mn);
        ps += (p0 + p1) + (p2 + p3);
        pf0u.u[c >> 1] = cvtpk(p0, p1);
        pf1u.u[c >> 1] = cvtpk(p2, p3);
      }
      ps += __shfl_xor(ps, 16);
      ps += __shfl_xor(ps, 32);
      m_state = mn;
      l_state = al * l_state + ps;
      if (lg == 0) haloL16[t & 1][r] = rawS16[pb][r][63];
      #pragma unroll
      for (int i = 0; i < 4; ++i) {
        float a = __shfl(al, lg * 4 + i);
        #pragma unroll
        for (int cb = 0; cb < 8; ++cb) oacc[cb][i] *= a;
      }
      const short* Vtile = VwH + (size_t)tp * 8192;
      #pragma unroll
      for (int kk = 0; kk < 2; ++kk) {
        bf16x8 pf = kk ? pf1u.v : pf0u.v;
        #pragma unroll
        for (int cb = 0; cb < 8; ++cb) {
          const short* vp = Vtile + (size_t)(cb * 16 + lm) * 64 + (kk * 4 + lg) * 8;
          bf16x8 vf = *(const bf16x8*)vp;
          oacc[cb] = __builtin_amdgcn_mfma_f32_16x16x32_bf16(pf, vf, oacc[cb], 0, 0, 0);
        }
      }
    }
  }

  // ---- epilogue (R4 verbatim) ----
  #pragma unroll
  for (int i = 0; i < 4; ++i) {
    int rr = wid * 16 + lg * 4 + i;
    int q = qr0 + rr;
    float lr = __shfl(l_state, lg * 4 + i);
    if (rr >= 2 && q <= q_cap) {
      float inv = 1.f / lr;
      #pragma unroll
      for (int cb = 0; cb < 8; ++cb) {
        Oh[(size_t)q * DIM + cb * 16 + lm] = oacc[cb][i] * inv;
      }
    }
  }
}

extern "C" void kernel_launch(void* const* d_in, const int* in_sizes, int n_in,
                              void* d_out, int out_size, void* d_ws, size_t ws_size,
                              hipStream_t stream) {
  const float* Q = (const float*)d_in[0];
  const float* K = (const float*)d_in[1];
  const float* V = (const float*)d_in[2];
  const float* W = (const float*)d_in[3];
  float* Out = (float*)d_out;

  short* Kb = (short*)d_ws;                        // 8 MiB
  short* Vw = (short*)((char*)d_ws + 8388608);     // 8 MiB (total exactly 16 MiB)

  prep_k<<<dim3(2048), 256, 0, stream>>>(K, Kb);
  prep_v<<<dim3(32, NHEAD), 256, 0, stream>>>(V, Vw);

  convattn_main<<<dim3(544), 256, 0, stream>>>(Q, Kb, Vw, W, Out);
}

// Round 11
// 159.208 us; speedup vs baseline: 1.6521x; 1.6521x over previous
//
#include <hip/hip_runtime.h>
#include <hip/hip_bf16.h>
#include <math.h>

#define S_LEN 2048
#define DIM   128
#define NHEAD 16
#define BQ    62
#define BK    64
#define SCALE 0.08838834764831845f

typedef __attribute__((ext_vector_type(8))) short bf16x8;
typedef __attribute__((ext_vector_type(4))) float f32x4;
typedef __attribute__((ext_vector_type(2))) float f32x2;

__device__ __forceinline__ short f2bf(float f) {
  union { float f; unsigned u; } v; v.f = f;
  unsigned r = v.u + 0x7fffu + ((v.u >> 16) & 1u);
  return (short)(r >> 16);
}
__device__ __forceinline__ unsigned cvtpk(float lo, float hi) {
  unsigned r;
  asm("v_cvt_pk_bf16_f32 %0, %1, %2" : "=v"(r) : "v"(lo), "v"(hi));
  return r;
}
__device__ __forceinline__ f32x2 pkfma(f32x2 a, f32x2 b, f32x2 c) {
  f32x2 d;
  asm("v_pk_fma_f32 %0, %1, %2, %3" : "=v"(d) : "v"(a), "v"(b), "v"(c));
  return d;
}
__device__ __forceinline__ void gll16(const void* gsrc, void* ldst) {
  __builtin_amdgcn_global_load_lds(
      (const __attribute__((address_space(1))) void*)gsrc,
      (__attribute__((address_space(3))) void*)ldst, 16, 0, 0);
}

// ---------- prep 1: K fp32 -> bf16*SCALE, 16B-chunk XOR-swizzled (R4 verbatim) ----------
__global__ __launch_bounds__(256)
void prep_k(const float* __restrict__ K, short* __restrict__ Kb) {
  int gid = blockIdx.x * 256 + threadIdx.x;
  int chunk = gid & 15;
  int row = gid >> 4;                       // h*2048 + k
  int k = row & (S_LEN - 1);
  const float* src = K + (size_t)row * DIM + chunk * 8;
  float4 a = *(const float4*)(src);
  float4 b = *(const float4*)(src + 4);
  bf16x8 o;
  o[0]=f2bf(a.x*SCALE); o[1]=f2bf(a.y*SCALE); o[2]=f2bf(a.z*SCALE); o[3]=f2bf(a.w*SCALE);
  o[4]=f2bf(b.x*SCALE); o[5]=f2bf(b.y*SCALE); o[6]=f2bf(b.z*SCALE); o[7]=f2bf(b.w*SCALE);
  int cp = (chunk & 8) | ((chunk & 7) ^ (k & 7));
  *(bf16x8*)(Kb + (size_t)row * DIM + cp * 8) = o;
}

// ---------- prep 2: V fp32 -> V^T bf16 tiles [h][tile64][d][64], plain (R9 verbatim) ----------
__global__ __launch_bounds__(256)
void prep_v(const float* __restrict__ V, short* __restrict__ Vw) {
  __shared__ __align__(16) short lv[128][72];
  int tile = blockIdx.x, h = blockIdx.y;
  const float* src = V + ((size_t)h * S_LEN + tile * 64) * DIM;
  int kr = threadIdx.x >> 2, dc = (threadIdx.x & 3) * 32;
  const float* sp = src + (size_t)kr * DIM + dc;
  #pragma unroll
  for (int j = 0; j < 32; j += 4) {
    float4 v = *(const float4*)(sp + j);
    lv[dc + j][kr]     = f2bf(v.x);
    lv[dc + j + 1][kr] = f2bf(v.y);
    lv[dc + j + 2][kr] = f2bf(v.z);
    lv[dc + j + 3][kr] = f2bf(v.w);
  }
  __syncthreads();
  int d = threadIdx.x >> 1, cbase = (threadIdx.x & 1) * 4;
  short* dst = Vw + ((size_t)h * 32 + tile) * 8192 + (size_t)d * 64;
  #pragma unroll
  for (int c0 = 0; c0 < 4; ++c0) {
    int c = cbase + c0;
    *(bf16x8*)(dst + c * 8) = *(const bf16x8*)&lv[d][c * 8];
  }
}

// ---------- main: R4's lag-1 pipeline with (1) paired-fp32 rawF (f32x2 = cols
// {c,c+32}, so conv ds_read_b64 halves ARE the pkfma chunk pair — no unpacking),
// (2) V^T PV fragments direct from global (L2-resident; latency at iter tail),
// (3) setprio around MFMA clusters. K staging via global_load_lds + vmcnt(4)
// (in-order retirement: K[t] provably drained by prior Phase C's V-loads). ----------
__global__ __launch_bounds__(256, 2)
void convattn_main(const float* __restrict__ Q, const short* __restrict__ Kb,
                   const short* __restrict__ Vw, const float* __restrict__ Wt,
                   float* __restrict__ Out) {
  __shared__ __align__(16) short Kt2[2][64][128];   // 32 KB (swizzle lives in data)
  __shared__ __align__(16) float rawF[2][64][70];   // 35.8 KB; pair j: dwords {2j,2j+1} = cols {j-2, j+30}
  __shared__ float haloLF[2][64];                   // 0.5 KB

  const int bx = blockIdx.x;
  const int rank = (bx < 256) ? bx : ((bx < 512) ? (767 - bx) : bx);
  const int qt = 33 - (rank >> 4);                  // longest-first
  const int h  = rank & 15;
  const int q0 = qt * BQ;
  const int qr0 = q0 - 2;
  const int q_cap = min(q0 + BQ - 1, S_LEN - 1);
  const int T = q_cap / BK + 1;

  const int tid  = threadIdx.x;
  const int wid  = tid >> 6;
  const int lane = tid & 63;
  const int lm   = lane & 15;
  const int lg   = lane >> 4;

  const float* Qh = Q + (size_t)h * S_LEN * DIM;
  const short* KbH = Kb + (size_t)h * S_LEN * DIM;
  const short* VwH = Vw + (size_t)h * 32 * 8192;
  float* Oh = Out + (size_t)h * S_LEN * DIM;

  f32x2 wp[9];
  #pragma unroll
  for (int i = 0; i < 9; ++i) { float w = Wt[h * 9 + i]; wp[i][0] = w; wp[i][1] = w; }

  // ---- Q fragments (bf16), hoisted (R4 verbatim) ----
  bf16x8 qf[4];
  {
    int qrow = qr0 + wid * 16 + lm;
    int qc = qrow < 0 ? 0 : (qrow >= S_LEN ? S_LEN - 1 : qrow);
    const float* qp = Qh + (size_t)qc * DIM;
    #pragma unroll
    for (int kk = 0; kk < 4; ++kk) {
      int d0 = kk * 32 + lg * 8;
      float4 a = *(const float4*)(qp + d0);
      float4 b = *(const float4*)(qp + d0 + 4);
      bf16x8 f;
      f[0]=f2bf(a.x); f[1]=f2bf(a.y); f[2]=f2bf(a.z); f[3]=f2bf(a.w);
      f[4]=f2bf(b.x); f[5]=f2bf(b.y); f[6]=f2bf(b.z); f[7]=f2bf(b.w);
      qf[kk] = f;
    }
  }
  if (tid < 64) haloLF[0][tid] = 0.f;

  float m_state = -INFINITY, l_state = 0.f;
  f32x4 oacc[8];
  const f32x4 zero4 = {0.f, 0.f, 0.f, 0.f};
  #pragma unroll
  for (int cb = 0; cb < 8; ++cb) oacc[cb] = zero4;

  // drain prologue VGPR loads, then stage K tile 0
  __builtin_amdgcn_sched_barrier(0);
  asm volatile("s_waitcnt vmcnt(0)" ::: "memory");
  __builtin_amdgcn_sched_barrier(0);
  {
    #pragma unroll
    for (int i = 0; i < 4; ++i) {
      int off = wid * 4096 + i * 1024;
      gll16((const char*)KbH + off + lane * 16, (char*)&Kt2[0][0][0] + off);
    }
  }

  for (int t = 0; t <= T; ++t) {
    // B1: all waves done with previous Phase C LDS reads / haloLF writes
    asm volatile("s_waitcnt lgkmcnt(0)" ::: "memory");
    __builtin_amdgcn_sched_barrier(0);
    __builtin_amdgcn_s_barrier();
    // issue K[t+1] DMA (clamped at the end; redundant loads are harmless)
    {
      int ksrc = (t + 1 < T) ? t + 1 : T - 1;
      const char* kg = (const char*)(KbH + (size_t)ksrc * BK * DIM);
      char* kl = (char*)&Kt2[(t + 1) & 1][0][0];
      #pragma unroll
      for (int i = 0; i < 4; ++i) {
        int off = wid * 4096 + i * 1024;
        gll16(kg + off + lane * 16, kl + off);
      }
    }
    // B2: K[t] resident (the 4 newest = K[t+1] just issued stay in flight)
    asm volatile("s_waitcnt vmcnt(4)" ::: "memory");
    __builtin_amdgcn_sched_barrier(0);
    __builtin_amdgcn_s_barrier();
    // ---- Phase B: QK^T -> masked fp32 pair-layout tile t ----
    if (t < T) {
      const short(*Ktile)[128] = Kt2[t & 1];
      int k0 = t * BK;
      f32x4 sacc[4];
      #pragma unroll
      for (int cb = 0; cb < 4; ++cb) sacc[cb] = zero4;
      __builtin_amdgcn_s_setprio(1);
      #pragma unroll
      for (int kk = 0; kk < 4; ++kk) {
        #pragma unroll
        for (int cb = 0; cb < 4; ++cb) {
          int c = kk * 4 + lg;
          int cp = (c & 8) | ((c & 7) ^ (lm & 7));
          bf16x8 bf = *(const bf16x8*)((const char*)&Ktile[cb * 16 + lm][0] + cp * 16);
          sacc[cb] = __builtin_amdgcn_mfma_f32_16x16x32_bf16(qf[kk], bf, sacc[cb], 0, 0, 0);
        }
      }
      __builtin_amdgcn_s_setprio(0);
      const int buf = t & 1;
      #pragma unroll
      for (int cb = 0; cb < 4; ++cb) {
        int rr = wid * 16 + lg * 4;
        int cc = cb * 16 + lm;
        int di = ((cc & 31) + 2) * 2 + (cc >> 5);   // pair j=(cc&31)+2, comp cc>>5
        #pragma unroll
        for (int i = 0; i < 4; ++i) {
          float v = ((k0 + cc) <= (qr0 + rr + i)) ? sacc[cb][i] : 0.f;
          rawF[buf][rr + i][di] = v;
        }
      }
    }
    // B3: publish rawF tile t cross-wave
    asm volatile("s_waitcnt lgkmcnt(0)" ::: "memory");
    __builtin_amdgcn_sched_barrier(0);
    __builtin_amdgcn_s_barrier();
    // ---- Phase C: paired conv + online softmax + PV for tile t-1 ----
    if (t > 0) {
      const int tp = t - 1;
      const int pb = tp & 1, nb = pb ^ 1;
      const int c0p = tp * BK;
      const bool haveRight = (t < T);
      const int r = wid * 16 + lm;
      const int q = qr0 + r;
      const bool rowvalid = (r >= 2) && (q <= q_cap);
      const int a0 = max(r - 2, 0), a1 = max(r - 1, 0);
      const int ridx[3] = { a0, a1, r };
      const f32x2* rp[3] = { (const f32x2*)&rawF[pb][a0][0],
                             (const f32x2*)&rawF[pb][a1][0],
                             (const f32x2*)&rawF[pb][r][0] };
      const int cs0 = lg * 8;
      const int cs1 = 32 + lg * 8;
      const int jb = lg * 8 + 1;              // pair idx of cols {cs0-1, cs1-1}

      // xv[rw][i] = {col cs0-1+i, col cs1-1+i}; edge fixups for lg==0 / lg==3
      f32x2 xv[3][10];
      #pragma unroll
      for (int rw = 0; rw < 3; ++rw) {
        #pragma unroll
        for (int i = 0; i < 10; ++i) xv[rw][i] = rp[rw][jb + i];
      }
      if (lg == 0) {
        #pragma unroll
        for (int rw = 0; rw < 3; ++rw) {
          xv[rw][0][0] = haloLF[pb][ridx[rw]];   // col -1
          xv[rw][0][1] = rp[rw][33][0];          // col 31
        }
      }
      if (lg == 3) {
        #pragma unroll
        for (int rw = 0; rw < 3; ++rw) {
          xv[rw][9][0] = rp[rw][2][1];           // col 32
          xv[rw][9][1] = haveRight               // col 64 = next tile col 0
              ? ((const f32x2*)&rawF[nb][ridx[rw]][0])[2][0] : 0.f;
        }
      }

      const int thr0 = rowvalid ? (q - c0p - cs0) : -1;
      const int thr1 = rowvalid ? (q - c0p - cs1) : -1;
      float svx[8], svy[8];
      float pm = -INFINITY;
      #pragma unroll
      for (int c = 0; c < 8; ++c) {
        f32x2 acc = {0.f, 0.f};
        acc = pkfma(wp[0], xv[0][c],     acc);
        acc = pkfma(wp[1], xv[0][c + 1], acc);
        acc = pkfma(wp[2], xv[0][c + 2], acc);
        acc = pkfma(wp[3], xv[1][c],     acc);
        acc = pkfma(wp[4], xv[1][c + 1], acc);
        acc = pkfma(wp[5], xv[1][c + 2], acc);
        acc = pkfma(wp[6], xv[2][c],     acc);
        acc = pkfma(wp[7], xv[2][c + 1], acc);
        acc = pkfma(wp[8], xv[2][c + 2], acc);
        svx[c] = (c <= thr0) ? acc[0] : -INFINITY;
        svy[c] = (c <= thr1) ? acc[1] : -INFINITY;
        pm = fmaxf(pm, fmaxf(svx[c], svy[c]));
      }
      pm = fmaxf(pm, __shfl_xor(pm, 16));
      pm = fmaxf(pm, __shfl_xor(pm, 32));
      const float mn = fmaxf(m_state, pm);
      const float al = __expf(m_state - mn);
      float ps = 0.f;
      union { bf16x8 v; unsigned u[4]; } pf0u, pf1u;
      #pragma unroll
      for (int c = 0; c < 8; c += 2) {
        float p0 = __expf(svx[c] - mn);
        float p1 = __expf(svx[c + 1] - mn);
        float p2 = __expf(svy[c] - mn);
        float p3 = __expf(svy[c + 1] - mn);
        ps += (p0 + p1) + (p2 + p3);
        pf0u.u[c >> 1] = cvtpk(p0, p1);
        pf1u.u[c >> 1] = cvtpk(p2, p3);
      }
      ps += __shfl_xor(ps, 16);
      ps += __shfl_xor(ps, 32);
      m_state = mn;
      l_state = al * l_state + ps;
      if (lg == 0) haloLF[t & 1][r] = rawF[pb][r][67];   // pair 33 .y = col 63
      #pragma unroll
      for (int i = 0; i < 4; ++i) {
        float a = __shfl(al, lg * 4 + i);
        #pragma unroll
        for (int cb = 0; cb < 8; ++cb) oacc[cb][i] *= a;
      }
      const short* Vtile = VwH + (size_t)tp * 8192;
      __builtin_amdgcn_s_setprio(1);
      #pragma unroll
      for (int kk = 0; kk < 2; ++kk) {
        bf16x8 pf = kk ? pf1u.v : pf0u.v;
        #pragma unroll
        for (int cb = 0; cb < 8; ++cb) {
          const short* vp = Vtile + (size_t)(cb * 16 + lm) * 64 + (kk * 4 + lg) * 8;
          bf16x8 vf = *(const bf16x8*)vp;
          oacc[cb] = __builtin_amdgcn_mfma_f32_16x16x32_bf16(pf, vf, oacc[cb], 0, 0, 0);
        }
      }
      __builtin_amdgcn_s_setprio(0);
    }
  }

  // drain dangling prefetch DMA before the block retires
  asm volatile("s_waitcnt vmcnt(0)" ::: "memory");

  // ---- epilogue (R4 verbatim) ----
  #pragma unroll
  for (int i = 0; i < 4; ++i) {
    int rr = wid * 16 + lg * 4 + i;
    int q = qr0 + rr;
    float lr = __shfl(l_state, lg * 4 + i);
    if (rr >= 2 && q <= q_cap) {
      float inv = 1.f / lr;
      #pragma unroll
      for (int cb = 0; cb < 8; ++cb) {
        Oh[(size_t)q * DIM + cb * 16 + lm] = oacc[cb][i] * inv;
      }
    }
  }
}

extern "C" void kernel_launch(void* const* d_in, const int* in_sizes, int n_in,
                              void* d_out, int out_size, void* d_ws, size_t ws_size,
                              hipStream_t stream) {
  const float* Q = (const float*)d_in[0];
  const float* K = (const float*)d_in[1];
  const float* V = (const float*)d_in[2];
  const float* W = (const float*)d_in[3];
  float* Out = (float*)d_out;

  short* Kb = (short*)d_ws;                        // 8 MiB
  short* Vw = (short*)((char*)d_ws + 8388608);     // 8 MiB (total exactly 16 MiB)

  prep_k<<<dim3(2048), 256, 0, stream>>>(K, Kb);
  prep_v<<<dim3(32, NHEAD), 256, 0, stream>>>(V, Vw);

  convattn_main<<<dim3(544), 256, 0, stream>>>(Q, Kb, Vw, W, Out);
}

// Round 12
// 128.700 us; speedup vs baseline: 2.0438x; 1.2370x over previous
//
#include <hip/hip_runtime.h>
#include <hip/hip_bf16.h>
#include <math.h>

#define S_LEN 2048
#define DIM   128
#define NHEAD 16
#define BQ    56          // 4 waves x 14 conv rows (wave-private 16-row raw tiles)
#define BK    32
#define SCALE 0.08838834764831845f

typedef __attribute__((ext_vector_type(8))) short bf16x8;
typedef __attribute__((ext_vector_type(4))) float f32x4;
typedef __attribute__((ext_vector_type(2))) float f32x2;

__device__ __forceinline__ short f2bf(float f) {
  union { float f; unsigned u; } v; v.f = f;
  unsigned r = v.u + 0x7fffu + ((v.u >> 16) & 1u);
  return (short)(r >> 16);
}
__device__ __forceinline__ float bhi(unsigned u) {
  union { unsigned v; float f; } x; x.v = u & 0xffff0000u; return x.f;
}
__device__ __forceinline__ float blo(unsigned u) {
  union { unsigned v; float f; } x; x.v = u << 16; return x.f;
}
__device__ __forceinline__ float b2f(short s) {
  union { unsigned v; float f; } x; x.v = ((unsigned)(unsigned short)s) << 16; return x.f;
}
__device__ __forceinline__ unsigned cvtpk(float lo, float hi) {
  unsigned r;
  asm("v_cvt_pk_bf16_f32 %0, %1, %2" : "=v"(r) : "v"(lo), "v"(hi));
  return r;
}
__device__ __forceinline__ f32x2 pkfma(f32x2 a, f32x2 b, f32x2 c) {
  f32x2 d;
  asm("v_pk_fma_f32 %0, %1, %2, %3" : "=v"(d) : "v"(a), "v"(b), "v"(c));
  return d;
}
__device__ __forceinline__ void gll16(const void* gsrc, void* ldst) {
  __builtin_amdgcn_global_load_lds(
      (const __attribute__((address_space(1))) void*)gsrc,
      (__attribute__((address_space(3))) void*)ldst, 16, 0, 0);
}

// ---------- prep 1: K fp32 -> bf16*SCALE, 16B-chunk XOR-swizzled by k&7 (R4 verbatim) ----------
__global__ __launch_bounds__(256)
void prep_k(const float* __restrict__ K, short* __restrict__ Kb) {
  int gid = blockIdx.x * 256 + threadIdx.x;
  int chunk = gid & 15;
  int row = gid >> 4;                       // h*2048 + k
  int k = row & (S_LEN - 1);
  const float* src = K + (size_t)row * DIM + chunk * 8;
  float4 a = *(const float4*)(src);
  float4 b = *(const float4*)(src + 4);
  bf16x8 o;
  o[0]=f2bf(a.x*SCALE); o[1]=f2bf(a.y*SCALE); o[2]=f2bf(a.z*SCALE); o[3]=f2bf(a.w*SCALE);
  o[4]=f2bf(b.x*SCALE); o[5]=f2bf(b.y*SCALE); o[6]=f2bf(b.z*SCALE); o[7]=f2bf(b.w*SCALE);
  int cp = (chunk & 8) | ((chunk & 7) ^ (k & 7));
  *(bf16x8*)(Kb + (size_t)row * DIM + cp * 8) = o;
}

// ---------- prep 2: V fp32 -> V^T bf16 tiles [h][tile32][d][32],
// 16B chunk swizzled by c ^ (d&3) ^ ((d>>2)&3)  (2-way banks on PV b128 reads) ----------
__global__ __launch_bounds__(256)
void prep_v(const float* __restrict__ V, short* __restrict__ Vw) {
  __shared__ short lv[32][132];
  int h = blockIdx.y, vt = blockIdx.x;
  const float* src = V + ((size_t)h * S_LEN + vt * 32) * DIM;
  int kr = threadIdx.x >> 3, c16 = (threadIdx.x & 7) * 16;
  const float* sp = src + (size_t)kr * DIM + c16;
  #pragma unroll
  for (int j = 0; j < 16; j += 4) {
    float4 v = *(const float4*)(sp + j);
    lv[kr][c16 + j]     = f2bf(v.x);
    lv[kr][c16 + j + 1] = f2bf(v.y);
    lv[kr][c16 + j + 2] = f2bf(v.z);
    lv[kr][c16 + j + 3] = f2bf(v.w);
  }
  __syncthreads();
  int d = threadIdx.x >> 1, half = threadIdx.x & 1;
  short* dst = Vw + ((size_t)(h * 64 + vt)) * 4096 + (size_t)d * 32;
  int sw = (d & 3) ^ ((d >> 2) & 3);
  #pragma unroll
  for (int cc = 0; cc < 2; ++cc) {
    int c = half * 2 + cc;
    bf16x8 o;
    #pragma unroll
    for (int e = 0; e < 8; ++e) o[e] = lv[c * 8 + e][d];
    *(bf16x8*)(dst + ((c ^ sw) * 8)) = o;
  }
}

// ---------- main: wave-private-row lag-1 pipeline, BK=32, 2 barriers/iter.
// Wave w owns conv rows [q0+14w, q0+14w+14); its 16-row raw tile starts at
// q0+14w-2, so conv needs ONLY its own rows -> Phase B -> Phase C is same-wave
// (no barrier; compiler lgkmcnt orders rawS). V prefetched one iter early so
// the single vmcnt(4)+barrier (B2) covers both K[t] and V[t-1]. After B2, waves
// drift independently through QK^T / conv / softmax / PV (MFMA-VALU overlap). ----------
__global__ __launch_bounds__(256, 2)
void convattn_main(const float* __restrict__ Q, const short* __restrict__ Kb,
                   const short* __restrict__ Vw, const float* __restrict__ Wt,
                   float* __restrict__ Out) {
  __shared__ __align__(16) short Kt2[2][32][128];   // 16 KB
  __shared__ __align__(16) short Vt2[2][128][32];   // 16 KB (chunk-swizzled data)
  __shared__ __align__(16) short rawS[2][64][34];   // 8.5 KB, wave-private 16-row bands
  __shared__ float haloL[2][64];                    // 0.5 KB, per raw row

  const int bx = blockIdx.x;
  const int rank = (bx < 296) ? bx : (887 - bx);    // complementary pairing
  const int qt = 36 - (rank >> 4);                  // longest-first, 37 q-tiles
  const int h  = rank & 15;
  const int q0 = qt * BQ;
  const int q_cap = min(q0 + BQ - 1, S_LEN - 1);
  const int T = q_cap / BK + 1;

  const int tid  = threadIdx.x;
  const int wid  = tid >> 6;
  const int lane = tid & 63;
  const int lm   = lane & 15;
  const int lg   = lane >> 4;

  const int rbase = q0 + 14 * wid - 2;              // wave's raw row 0

  const float* Qh = Q + (size_t)h * S_LEN * DIM;
  const short* KbH = Kb + (size_t)h * S_LEN * DIM;
  const short* VwH = Vw + (size_t)h * 64 * 4096;
  float* Oh = Out + (size_t)h * S_LEN * DIM;

  f32x2 wp[9];
  #pragma unroll
  for (int i = 0; i < 9; ++i) { float w = Wt[h * 9 + i]; wp[i][0] = w; wp[i][1] = w; }

  // ---- Q fragments: raw row rbase+lm, clamped (mask kills out-of-range) ----
  bf16x8 qf[4];
  {
    int qrow = rbase + lm;
    int qc = qrow < 0 ? 0 : (qrow >= S_LEN ? S_LEN - 1 : qrow);
    const float* qp = Qh + (size_t)qc * DIM;
    #pragma unroll
    for (int kk = 0; kk < 4; ++kk) {
      int d0 = kk * 32 + lg * 8;
      float4 a = *(const float4*)(qp + d0);
      float4 b = *(const float4*)(qp + d0 + 4);
      bf16x8 f;
      f[0]=f2bf(a.x); f[1]=f2bf(a.y); f[2]=f2bf(a.z); f[3]=f2bf(a.w);
      f[4]=f2bf(b.x); f[5]=f2bf(b.y); f[6]=f2bf(b.z); f[7]=f2bf(b.w);
      qf[kk] = f;
    }
  }
  if (tid < 64) haloL[0][tid] = 0.f;

  float m_state = -INFINITY, l_state = 0.f;
  f32x4 oacc[8];
  const f32x4 zero4 = {0.f, 0.f, 0.f, 0.f};
  #pragma unroll
  for (int cb = 0; cb < 8; ++cb) oacc[cb] = zero4;

  // drain prologue VGPR loads so counted vmcnt is exact; stage K[0]
  __builtin_amdgcn_sched_barrier(0);
  asm volatile("s_waitcnt vmcnt(0)" ::: "memory");
  __builtin_amdgcn_sched_barrier(0);
  {
    #pragma unroll
    for (int i = 0; i < 2; ++i) {
      int off = wid * 2048 + i * 1024;
      gll16((const char*)KbH + off + lane * 16, (char*)&Kt2[0][0][0] + off);
    }
  }

  for (int t = 0; t <= T; ++t) {
    // B1: all waves done with previous iteration's LDS reads
    asm volatile("s_waitcnt lgkmcnt(0)" ::: "memory");
    __builtin_amdgcn_sched_barrier(0);
    __builtin_amdgcn_s_barrier();
    // issue V[t] (consumed next iter) and K[t+1] (consumed next iter)
    {
      int vsrc = (t < T) ? t : T - 1;
      int ksrc = (t + 1 < T) ? t + 1 : T - 1;
      const char* vg = (const char*)(VwH + (size_t)vsrc * 4096);
      const char* kg = (const char*)(KbH + (size_t)ksrc * BK * DIM);
      char* vl = (char*)&Vt2[t & 1][0][0];
      char* kl = (char*)&Kt2[(t + 1) & 1][0][0];
      #pragma unroll
      for (int i = 0; i < 2; ++i) {
        int off = wid * 2048 + i * 1024;
        gll16(vg + off + lane * 16, vl + off);
      }
      #pragma unroll
      for (int i = 0; i < 2; ++i) {
        int off = wid * 2048 + i * 1024;
        gll16(kg + off + lane * 16, kl + off);
      }
    }
    // B2: K[t] and V[t-1] (issued last iter) resident; 4 newest stay in flight
    asm volatile("s_waitcnt vmcnt(4)" ::: "memory");
    __builtin_amdgcn_sched_barrier(0);
    __builtin_amdgcn_s_barrier();
    // ======== from here to loop end: no cross-wave sync — waves drift ========
    // ---- Phase B: QK^T tile t -> masked bf16 rawS[t&1] (own 16-row band) ----
    if (t < T) {
      const short(*Ktile)[128] = Kt2[t & 1];
      const int k0 = t * BK;
      f32x4 sacc0 = zero4, sacc1 = zero4;
      __builtin_amdgcn_s_setprio(1);
      #pragma unroll
      for (int kk = 0; kk < 4; ++kk) {
        #pragma unroll
        for (int cb = 0; cb < 2; ++cb) {
          int kloc = cb * 16 + lm;
          int c = kk * 4 + lg;
          int cp = (c & 8) | ((c & 7) ^ (kloc & 7));
          bf16x8 bf = *(const bf16x8*)((const char*)&Ktile[kloc][0] + cp * 16);
          if (cb == 0) sacc0 = __builtin_amdgcn_mfma_f32_16x16x32_bf16(qf[kk], bf, sacc0, 0, 0, 0);
          else         sacc1 = __builtin_amdgcn_mfma_f32_16x16x32_bf16(qf[kk], bf, sacc1, 0, 0, 0);
        }
      }
      __builtin_amdgcn_s_setprio(0);
      const int buf = t & 1;
      #pragma unroll
      for (int cb = 0; cb < 2; ++cb) {
        int rr = wid * 16 + lg * 4;
        int cc = cb * 16 + lm;
        int qa = rbase + lg * 4;              // raw row of acc elem 0
        #pragma unroll
        for (int i = 0; i < 4; i += 2) {
          float s0 = cb ? sacc1[i] : sacc0[i];
          float s1 = cb ? sacc1[i + 1] : sacc0[i + 1];
          float v0 = ((k0 + cc) <= (qa + i))     ? s0 : 0.f;
          float v1 = ((k0 + cc) <= (qa + i + 1)) ? s1 : 0.f;
          unsigned pk = cvtpk(v0, v1);
          rawS[buf][rr + i][cc]     = (short)pk;
          rawS[buf][rr + i + 1][cc] = (short)(pk >> 16);
        }
      }
    }
    // ---- Phase C (t>0): conv + softmax + PV for tile t-1, all same-wave ----
    if (t > 0) {
      const int tc = t - 1;
      const int pb = tc & 1, nb = t & 1;
      const int k0p = tc * BK;
      const bool haveRight = (t < T);
      const int m = lm;                        // own conv row
      const int qo = rbase + m;                // output q row
      const bool rowvalid = (m >= 2) && (qo < S_LEN);
      const int R0 = wid * 16 + max(m - 2, 0);
      const int R1 = wid * 16 + max(m - 1, 0);
      const int R2 = wid * 16 + m;
      const int cs = lg * 8;
      const bool leftEdge  = (lg == 0);
      const bool rightEdge = (lg == 3);
      const int cA = leftEdge ? 0 : cs - 2;
      const int Rr[3] = { R0, R1, R2 };

      float x[3][10];                          // cols cs-1 .. cs+8
      #pragma unroll
      for (int rw = 0; rw < 3; ++rw) {
        const short* p = &rawS[pb][Rr[rw]][0];
        unsigned aw = *(const unsigned*)(p + cA);
        unsigned w0 = *(const unsigned*)(p + cs);
        unsigned w1 = *(const unsigned*)(p + cs + 2);
        unsigned w2 = *(const unsigned*)(p + cs + 4);
        unsigned w3 = *(const unsigned*)(p + cs + 6);
        unsigned w4 = *(const unsigned*)(p + cs + 8);   // lg==3 hits pad (overridden)
        float hv = haloL[pb][Rr[rw]];
        float rv = 0.f;
        if (rightEdge && haveRight) rv = b2f(rawS[nb][Rr[rw]][0]);
        x[rw][0] = leftEdge ? hv : bhi(aw);
        x[rw][1] = blo(w0); x[rw][2] = bhi(w0);
        x[rw][3] = blo(w1); x[rw][4] = bhi(w1);
        x[rw][5] = blo(w2); x[rw][6] = bhi(w2);
        x[rw][7] = blo(w3); x[rw][8] = bhi(w3);
        x[rw][9] = rightEdge ? rv : blo(w4);
      }
      if (rightEdge) haloL[nb][wid * 16 + m] = x[2][8];   // col 31 of own row

      // packed conv: out pair (c, c+4); xs[rw][d] = {x[d], x[d+4]}
      const int thr = rowvalid ? (qo - k0p - cs) : -1;
      float p8[8];
      float pm = -INFINITY;
      #pragma unroll
      for (int c = 0; c < 4; ++c) {
        f32x2 acc = {0.f, 0.f};
        #pragma unroll
        for (int rw = 0; rw < 3; ++rw) {
          #pragma unroll
          for (int j = 0; j < 3; ++j) {
            f32x2 xp; xp[0] = x[rw][c + j]; xp[1] = x[rw][c + 4 + j];
            acc = pkfma(wp[rw * 3 + j], xp, acc);
          }
        }
        p8[c]     = (c <= thr)     ? acc[0] : -INFINITY;
        p8[c + 4] = (c + 4 <= thr) ? acc[1] : -INFINITY;
        pm = fmaxf(pm, fmaxf(p8[c], p8[c + 4]));
      }
      pm = fmaxf(pm, __shfl_xor(pm, 16));
      pm = fmaxf(pm, __shfl_xor(pm, 32));
      const float mn = fmaxf(m_state, pm);
      const float al = __expf(m_state - mn);
      float ps = 0.f;
      union { bf16x8 v; unsigned u[4]; } pfu;
      #pragma unroll
      for (int c = 0; c < 8; c += 2) {
        float e0 = __expf(p8[c] - mn);
        float e1 = __expf(p8[c + 1] - mn);
        ps += e0 + e1;
        pfu.u[c >> 1] = cvtpk(e0, e1);
      }
      ps += __shfl_xor(ps, 16);
      ps += __shfl_xor(ps, 32);
      m_state = mn;
      l_state = al * l_state + ps;
      #pragma unroll
      for (int i = 0; i < 4; ++i) {
        float a = __shfl(al, lg * 4 + i);
        #pragma unroll
        for (int cb = 0; cb < 8; ++cb) oacc[cb][i] *= a;
      }
      const short* Vbase = &Vt2[pb][0][0];
      const int cpv = lg ^ (lm & 3) ^ ((lm >> 2) & 3);
      __builtin_amdgcn_s_setprio(1);
      #pragma unroll
      for (int cb = 0; cb < 8; ++cb) {
        int d = cb * 16 + lm;
        bf16x8 vf = *(const bf16x8*)(Vbase + (size_t)d * 32 + cpv * 8);
        oacc[cb] = __builtin_amdgcn_mfma_f32_16x16x32_bf16(pfu.v, vf, oacc[cb], 0, 0, 0);
      }
      __builtin_amdgcn_s_setprio(0);
    }
  }

  // drain dangling prefetch DMA before the block retires
  asm volatile("s_waitcnt vmcnt(0)" ::: "memory");

  // ---- epilogue: wave-private rows [q0+14w, q0+14w+14) ----
  #pragma unroll
  for (int i = 0; i < 4; ++i) {
    int mrow = lg * 4 + i;
    int qo = rbase + mrow;
    float lr = __shfl(l_state, lg * 4 + i);
    if (mrow >= 2 && qo < S_LEN) {
      float inv = 1.f / lr;
      #pragma unroll
      for (int cb = 0; cb < 8; ++cb) {
        Oh[(size_t)qo * DIM + cb * 16 + lm] = oacc[cb][i] * inv;
      }
    }
  }
}

extern "C" void kernel_launch(void* const* d_in, const int* in_sizes, int n_in,
                              void* d_out, int out_size, void* d_ws, size_t ws_size,
                              hipStream_t stream) {
  const float* Q = (const float*)d_in[0];
  const float* K = (const float*)d_in[1];
  const float* V = (const float*)d_in[2];
  const float* W = (const float*)d_in[3];
  float* Out = (float*)d_out;

  short* Kb = (short*)d_ws;                        // 8 MiB
  short* Vw = (short*)((char*)d_ws + 8388608);     // 8 MiB (total exactly 16 MiB)

  prep_k<<<dim3(2048), 256, 0, stream>>>(K, Kb);
  prep_v<<<dim3(64, NHEAD), 256, 0, stream>>>(V, Vw);

  const int NQT = (S_LEN + BQ - 1) / BQ;           // 37
  convattn_main<<<dim3(NQT * NHEAD), 256, 0, stream>>>(Q, Kb, Vw, W, Out);
}